// Round 11
// baseline (4124.363 us; speedup 1.0000x reference)
//
#include <hip/hip_runtime.h>
#include <math.h>

// ---------------------------------------------------------------------------
// 2-layer LSTM, B=64 T=512 I=256 H=768, fp32 in/out.
// Round 11: r10 + per-wave flags (posted right after each wave's own vmcnt
// ack -- no end-barrier on the flag path) + chunk-granular consume (tight
// no-sleep poll of two 8B flag words per chunk, then 4 quanta + 4 MFMAs) +
// ring depth 16 with the L0/L1 guard at t-16 (off critical path).
// Traffic discipline (proven r5/r8/r9/r10): spin only on dedicated flag
// lines; touch data exactly once, after the ack'd flag guarantees it.
// ---------------------------------------------------------------------------

#define B_   64
#define T_   512
#define I_   256
#define H_   768
#define G4H  3072

constexpr size_t BTH = (size_t)B_ * T_ * H_;   // 25165824
constexpr size_t BH  = (size_t)B_ * H_;        // 49152

using f16_t = _Float16;
using f16x8 = __attribute__((ext_vector_type(8))) _Float16;
using f32x4 = __attribute__((ext_vector_type(4))) float;
typedef unsigned long long u64;

#define MFMA(a, b, c) __builtin_amdgcn_mfma_f32_16x16x32_f16((a), (b), (c), 0, 0, 0)

// Ring: quantum u64 = 4 f16 units. addr = slot*98304 + ws*1024 + q*512 + b*8.
#define SLOT_STRIDE 98304        // 96*64*16 bytes
#define RING_SLOTS  16
#define RING_BYTES  (RING_SLOTS * SLOT_STRIDE)

// Per-wave flags: wflag[t][ws][wp] u64 (wp = wave>>1); producer wave w posts
// 4B at half (w&1). Consumer polls the u64s for its two wave-pairs.
#define WFLAG_U64S  ((size_t)T_ * 96 * 4)      // 1.5 MB per layer

// LDS partition (bytes): WL 0..98304 | pre 98304..132096 | bsL ..132224
#define SMEM_BYTES 132224

// ---------------------------------------------------------------------------
__global__ void k_packW(const float* __restrict__ src, f16_t* __restrict__ dst,
                        int K, int KC, int total) {
  int i = blockIdx.x * blockDim.x + threadIdx.x;
  int stride = gridDim.x * blockDim.x;
  for (; i < total; i += stride) {
    int e = i & 7;
    int lane = (i >> 3) & 63;
    int rest = i >> 9;          // ptile*KC + kc
    int kc = rest % KC;
    int ptile = rest / KC;
    int p = ptile * 16 + (lane & 15);
    int k = kc * 32 + (lane >> 4) * 8 + e;
    int r = (p & 3) * H_ + (p >> 2);
    dst[i] = (f16_t)src[(size_t)r * K + k];
  }
}

__global__ void k_packX(const float* __restrict__ x, f16_t* __restrict__ dst) {
  int i = blockIdx.x * blockDim.x + threadIdx.x;
  int stride = gridDim.x * blockDim.x;
  const int total = 4 * T_ * 8 * 64 * 8;  // 8,388,608
  for (; i < total; i += stride) {
    int e = i & 7;
    int lane = (i >> 3) & 63;
    int kc = (i >> 9) & 7;
    int t = (i >> 12) & 511;
    int mtile = i >> 21;
    int b = mtile * 16 + (lane & 15);
    int k = kc * 32 + (lane >> 4) * 8 + e;
    dst[i] = (f16_t)x[((size_t)b * T_ + t) * I_ + k];
  }
}

__global__ void k_bias(const float* __restrict__ bih, const float* __restrict__ bhh,
                       float* __restrict__ bsum) {
  int p = blockIdx.x * blockDim.x + threadIdx.x;
  if (p < G4H) {
    int r = (p & 3) * H_ + (p >> 2);
    bsum[p] = bih[r] + bhh[r];
  }
}

__global__ void k_zero(int4* __restrict__ d, int n) {
  int i = blockIdx.x * blockDim.x + threadIdx.x;
  if (i < n) d[i] = make_int4(0, 0, 0, 0);
}

__device__ __forceinline__ float sigf(float v) {
  return __builtin_amdgcn_rcpf(1.0f + __builtin_amdgcn_exp2f(v * -1.44269504f));
}
__device__ __forceinline__ float tanhf_fast(float v) {
  return 2.0f * __builtin_amdgcn_rcpf(1.0f + __builtin_amdgcn_exp2f(v * -2.88539008f)) - 1.0f;
}

__device__ __forceinline__ u64 ld_q(const u64* p) {
  return __hip_atomic_load(p, __ATOMIC_RELAXED, __HIP_MEMORY_SCOPE_AGENT);
}
__device__ __forceinline__ unsigned ld_flag(const int* p) {
  return (unsigned)__hip_atomic_load(p, __ATOMIC_RELAXED, __HIP_MEMORY_SCOPE_AGENT);
}

// Off-critical-path guard: all 96 per-WG flags == tagv.
__device__ __forceinline__ void wait96(const int* f, unsigned tagv) {
  const int lane = threadIdx.x & 63;
  for (;;) {
    unsigned v0 = ld_flag(f + lane * 4);
    unsigned v1 = (lane < 32) ? ld_flag(f + (64 + lane) * 4) : tagv;
    if (__all((v0 == tagv) & (v1 == tagv))) return;
    __builtin_amdgcn_s_sleep(2);
  }
}

// Chunk-granular consume: per chunk, tight-poll the two wave-pair flag u64s
// (producer waves 2m0..2m0+4 cover batch rows [m0*16, m0*16+32)), then load
// the 4 data quanta once (flag-guaranteed settled) and MFMA.
template <int KCW>
__device__ __forceinline__ void consume(
    const char* sb, const u64* wf, int kcs, int l4, int l15, int m0,
    unsigned tagv, const f16_t* wl0, const f16_t* wl1,
    f32x4& a00, f32x4& a01, f32x4& a10, f32x4& a11) {
  const u64 exp = (u64)tagv * 0x100000001ULL;   // tagv in both halves
#pragma unroll
  for (int i = 0; i < KCW; ++i) {
    const int wsP = (kcs + i) * 4 + l4;
    const u64* f = wf + (size_t)wsP * 4 + m0;
    for (;;) {
      u64 f0 = ld_q(f);
      u64 f1 = ld_q(f + 1);
      if (__all((int)((f0 == exp) & (f1 == exp)))) break;
    }
    const u64* p = (const u64*)(sb + (size_t)wsP * 1024 +
                                (size_t)(m0 * 16 + l15) * 8);
    u64 v0 = ld_q(p);        // q0, row m0*16+l15
    u64 v1 = ld_q(p + 16);   // q0, row +16
    u64 v2 = ld_q(p + 64);   // q1, row
    u64 v3 = ld_q(p + 80);   // q1, row +16
    union { u64 q[2]; f16x8 f8; } cA, cB;
    cA.q[0] = v0; cA.q[1] = v2;
    cB.q[0] = v1; cB.q[1] = v3;
    f16x8 w0 = *(const f16x8*)(wl0 + (size_t)i * 512);
    f16x8 w1 = *(const f16x8*)(wl1 + (size_t)i * 512);
    a00 = MFMA(cA.f8, w0, a00);
    a01 = MFMA(cA.f8, w1, a01);
    a10 = MFMA(cB.f8, w0, a10);
    a11 = MFMA(cB.f8, w1, a11);
  }
}

// ---------------------------------------------------------------------------
// Persistent per-layer loop. 8 waves = mg(2) x kg(4); wave = 2x2 tile.
// L0: kg0 = x-GEMM (+ mg1: guard at t-16); kg1-3 consume h0[t-1].
// L1: kg0-1 consume h0[t]; kg2-3 consume h1[t-1].
// Per-wave flags carry consumer release; per-WG flags (post-barrier) feed
// only the depth-16 ring guard.
template <int KCW, bool IS_L1>
__device__ __forceinline__ void run_layer(
    int ws, const f16_t* __restrict__ Xf, const f16_t* __restrict__ Wihf,
    const f16_t* __restrict__ Whhf, const float* __restrict__ bsum,
    char* __restrict__ ring0c, char* __restrict__ ring1c,
    u64* __restrict__ wf0, u64* __restrict__ wf1,
    int* __restrict__ gf0, int* __restrict__ gf1,
    float* __restrict__ out, char* smem) {
  f16_t* WL = (f16_t*)smem;                              // [4 kg][2 p][KCW][512]
  float (*pre)[64][33] = (float (*)[64][33])(smem + 98304);
  float* bsL = (float*)(smem + 132096);                  // [32]

  const int tid = threadIdx.x;
  const int wave = tid >> 6, lane = tid & 63;
  const int kg = wave & 3, mg = wave >> 2;
  const int laneo = lane * 8;
  const int pt0 = ws * 2, m0 = mg * 2;
  const int l15 = lane & 15, l4 = lane >> 4;

  if (tid < 32) bsL[tid] = bsum[ws * 32 + tid];

  // ---- stage W into LDS (mg==0 waves) ----
  if (mg == 0) {
    const f16_t* src;
    int KC, kc0;
    if constexpr (!IS_L1) {
      if (kg == 0) { src = Wihf; KC = 8;  kc0 = 0; }
      else         { src = Whhf; KC = 24; kc0 = (kg - 1) * 8; }
    } else {
      if (kg < 2)  { src = Wihf; KC = 24; kc0 = kg * 12; }
      else         { src = Whhf; KC = 24; kc0 = (kg - 2) * 12; }
    }
#pragma unroll
    for (int p = 0; p < 2; ++p)
#pragma unroll
      for (int i = 0; i < KCW; ++i)
        *(uint4*)(WL + ((size_t)((kg * 2 + p) * KCW + i)) * 512 + laneo) =
            *(const uint4*)(src + ((size_t)(pt0 + p) * KC + kc0 + i) * 512 + laneo);
  }

  // Consumer chunk start (32-unit chunks of the source h vector).
  int kcs = 0;
  if constexpr (!IS_L1) kcs = (kg - 1) * 8;      // valid for kg>=1
  else                  kcs = (kg < 2) ? kg * 12 : (kg - 2) * 12;

  float c_reg = 0.f;
  const int u = tid & 7, b = tid >> 3;
  const int j = ws * 8 + u;
  char* myringc = IS_L1 ? ring1c : ring0c;
  u64* mywf = IS_L1 ? wf1 : wf0;
  int* mygf = IS_L1 ? gf1 : gf0;
  const f16_t* wl0 = WL + (size_t)(kg * 2) * KCW * 512 + laneo;
  const f16_t* wl1 = wl0 + (size_t)KCW * 512;

  __syncthreads();

  for (int t = 0; t < T_; ++t) {
    f32x4 a00 = {0.f, 0.f, 0.f, 0.f};
    f32x4 a01 = {0.f, 0.f, 0.f, 0.f};
    f32x4 a10 = {0.f, 0.f, 0.f, 0.f};
    f32x4 a11 = {0.f, 0.f, 0.f, 0.f};

    if constexpr (!IS_L1) {
      if (kg == 0) {
        // ring guard: before publishing h0[t] over h0[t-16]'s slot, all 96
        // L1 WGs must have finished step t-16 (=> consumed h0[t-16]).
        if (mg == 1 && t >= RING_SLOTS)
          wait96(gf1 + (size_t)(t - RING_SLOTS) * 128 * 4,
                 (unsigned)(t - RING_SLOTS + 1));
        // x_t @ Wih0^T (no recurrence dependency)
        const f16_t* A0 = Xf + ((size_t)m0 * T_ + t) * 4096 + laneo;
        const f16_t* A1 = A0 + (size_t)T_ * 4096;
#pragma unroll
        for (int i = 0; i < KCW; ++i) {
          f16x8 x0 = *(const f16x8*)(A0 + (size_t)i * 512);
          f16x8 x1 = *(const f16x8*)(A1 + (size_t)i * 512);
          f16x8 w0 = *(const f16x8*)(wl0 + (size_t)i * 512);
          f16x8 w1 = *(const f16x8*)(wl1 + (size_t)i * 512);
          a00 = MFMA(x0, w0, a00);
          a01 = MFMA(x0, w1, a01);
          a10 = MFMA(x1, w0, a10);
          a11 = MFMA(x1, w1, a11);
        }
      } else if (t >= 1) {
        consume<KCW>(ring0c + (size_t)((t - 1) & (RING_SLOTS - 1)) * SLOT_STRIDE,
                     wf0 + (size_t)(t - 1) * 384, kcs, l4, l15, m0,
                     (unsigned)t, wl0, wl1, a00, a01, a10, a11);
      }
    } else {
      const int srcstep = (kg < 2) ? t : t - 1;
      if (srcstep >= 0) {
        const char* sb = ((kg < 2) ? ring0c : ring1c) +
                         (size_t)(srcstep & (RING_SLOTS - 1)) * SLOT_STRIDE;
        const u64* wf = ((kg < 2) ? wf0 : wf1) + (size_t)srcstep * 384;
        consume<KCW>(sb, wf, kcs, l4, l15, m0, (unsigned)(srcstep + 1),
                     wl0, wl1, a00, a01, a10, a11);
      }
    }

    // ---- partial-sum exchange (C layout: col=lane&15, row=l4*4+r) ----
#pragma unroll
    for (int r = 0; r < 4; ++r) {
      pre[kg][m0 * 16 + l4 * 4 + r][l15]           = a00[r];
      pre[kg][m0 * 16 + l4 * 4 + r][16 + l15]      = a01[r];
      pre[kg][m0 * 16 + 16 + l4 * 4 + r][l15]      = a10[r];
      pre[kg][m0 * 16 + 16 + l4 * 4 + r][16 + l15] = a11[r];
    }
    __syncthreads();   // #1: pre complete -> gate

    // ---- gate phase: thread = (u = tid&7, b = tid>>3) ----
    float h;
    {
      float g0 = pre[0][b][4 * u + 0] + pre[1][b][4 * u + 0] + pre[2][b][4 * u + 0] + pre[3][b][4 * u + 0] + bsL[4 * u + 0];
      float g1 = pre[0][b][4 * u + 1] + pre[1][b][4 * u + 1] + pre[2][b][4 * u + 1] + pre[3][b][4 * u + 1] + bsL[4 * u + 1];
      float g2 = pre[0][b][4 * u + 2] + pre[1][b][4 * u + 2] + pre[2][b][4 * u + 2] + pre[3][b][4 * u + 2] + bsL[4 * u + 2];
      float g3 = pre[0][b][4 * u + 3] + pre[1][b][4 * u + 3] + pre[2][b][4 * u + 3] + pre[3][b][4 * u + 3] + bsL[4 * u + 3];
      float ig = sigf(g0), fg = sigf(g1), gg = tanhf_fast(g2), og = sigf(g3);
      c_reg = fg * c_reg + ig * gg;
      h = og * tanhf_fast(c_reg);

      // ring publish: gather 4 units via shfl, u%4==0 stores one u64 quantum.
      unsigned hb = (unsigned)__builtin_bit_cast(unsigned short, (f16_t)h);
      unsigned n1 = (unsigned)__shfl((int)hb, lane + 1);
      unsigned n2 = (unsigned)__shfl((int)hb, lane + 2);
      unsigned n3 = (unsigned)__shfl((int)hb, lane + 3);
      if ((u & 3) == 0) {
        u64 val = (u64)(hb | (n1 << 16)) | ((u64)(n2 | (n3 << 16)) << 32);
        u64* dst = (u64*)(myringc +
                          (size_t)(t & (RING_SLOTS - 1)) * SLOT_STRIDE +
                          (size_t)ws * 1024 + (u >> 2) * 512 + (size_t)b * 8);
        __hip_atomic_store(dst, val, __ATOMIC_RELAXED, __HIP_MEMORY_SCOPE_AGENT);
      }
    }
    // per-wave ack of own ring stores, then per-wave flag (no barrier!).
    asm volatile("s_waitcnt vmcnt(0)" ::: "memory");
    if (lane == 0) {
      unsigned* wfp = (unsigned*)(mywf + ((size_t)t * 96 + ws) * 4 + (wave >> 1));
      __hip_atomic_store(wfp + (wave & 1), (unsigned)(t + 1),
                         __ATOMIC_RELAXED, __HIP_MEMORY_SCOPE_AGENT);
    }

    // ---- deferred outputs (off critical path) ----
    if constexpr (IS_L1) {
      out[((size_t)b * T_ + t) * H_ + j] = h;  // ys
      if (t == T_ - 1) {
        out[BTH + BH + (size_t)b * H_ + j] = h;
        out[BTH + 3 * BH + (size_t)b * H_ + j] = c_reg;
      }
    } else {
      if (t == T_ - 1) {
        out[BTH + (size_t)b * H_ + j] = h;
        out[BTH + 2 * BH + (size_t)b * H_ + j] = c_reg;
      }
    }
    __syncthreads();   // #2: gate reads done -> pre reusable next step
    if (tid == 0)      // guard flag (only the t-16 ring guard reads it)
      __hip_atomic_store(mygf + ((size_t)t * 128 + ws) * 4, t + 1,
                         __ATOMIC_RELAXED, __HIP_MEMORY_SCOPE_AGENT);
  }
}

__launch_bounds__(512, 1)
__global__ void k_lstm(const f16_t* __restrict__ Xf,
                       const f16_t* __restrict__ Wih0f, const f16_t* __restrict__ Whh0f,
                       const f16_t* __restrict__ Wih1f, const f16_t* __restrict__ Whh1f,
                       const float* __restrict__ bsum0, const float* __restrict__ bsum1,
                       char* __restrict__ ring0c, char* __restrict__ ring1c,
                       u64* __restrict__ wf0, u64* __restrict__ wf1,
                       int* __restrict__ gf0, int* __restrict__ gf1,
                       float* __restrict__ out) {
  extern __shared__ char smem[];
  const int wg = blockIdx.x;
  if (wg < 96)
    run_layer<8, false>(wg, Xf, Wih0f, Whh0f, bsum0, ring0c, ring1c,
                        wf0, wf1, gf0, gf1, out, smem);
  else
    run_layer<12, true>(wg - 96, Xf, Wih1f, Whh1f, bsum1, ring0c, ring1c,
                        wf0, wf1, gf0, gf1, out, smem);
}

// ---------------------------------------------------------------------------
extern "C" void kernel_launch(void* const* d_in, const int* in_sizes, int n_in,
                              void* d_out, int out_size, void* d_ws, size_t ws_size,
                              hipStream_t stream) {
  const float* x    = (const float*)d_in[0];
  const float* wih0 = (const float*)d_in[1];
  const float* whh0 = (const float*)d_in[2];
  const float* bih0 = (const float*)d_in[3];
  const float* bhh0 = (const float*)d_in[4];
  const float* wih1 = (const float*)d_in[5];
  const float* whh1 = (const float*)d_in[6];
  const float* bih1 = (const float*)d_in[7];
  const float* bhh1 = (const float*)d_in[8];
  float* out = (float*)d_out;

  char* base = (char*)d_ws;
  size_t off = 0;
  auto take = [&](size_t bytes) -> char* {
    char* r = base + off;
    off = (off + bytes + 255) & ~(size_t)255;
    return r;
  };
  f16_t* Wih0f = (f16_t*)take((size_t)G4H * I_ * 2);
  f16_t* Whh0f = (f16_t*)take((size_t)G4H * H_ * 2);
  f16_t* Wih1f = (f16_t*)take((size_t)G4H * H_ * 2);
  f16_t* Whh1f = (f16_t*)take((size_t)G4H * H_ * 2);
  f16_t* Xf    = (f16_t*)take((size_t)4 * T_ * 8 * 64 * 8 * 2);
  float* bsum0 = (float*)take((size_t)G4H * 4);
  float* bsum1 = (float*)take((size_t)G4H * 4);
  // rings (flag-gated; no zero needed) + flags (zeroed each call)
  char* ring0c = take(RING_BYTES);
  char* ring1c = take(RING_BYTES);
  const size_t wfBytes = WFLAG_U64S * 8;                 // 1.5 MB each
  const size_t gfBytes = (size_t)T_ * 128 * 16;          // 1 MB each
  char* fl = take(2 * wfBytes + 2 * gfBytes);
  u64* wf0 = (u64*)fl;
  u64* wf1 = wf0 + WFLAG_U64S;
  int* gf0 = (int*)(fl + 2 * wfBytes);
  int* gf1 = gf0 + (size_t)T_ * 128 * 4;
  const size_t zeroBytes = 2 * wfBytes + 2 * gfBytes;    // 5.24 MB

  hipFuncSetAttribute(reinterpret_cast<const void*>(k_lstm),
                      hipFuncAttributeMaxDynamicSharedMemorySize, SMEM_BYTES);

  k_packW<<<768, 256, 0, stream>>>(wih0, Wih0f, I_, 8, G4H * I_);
  k_packW<<<2048, 256, 0, stream>>>(whh0, Whh0f, H_, 24, G4H * H_);
  k_packW<<<2048, 256, 0, stream>>>(wih1, Wih1f, H_, 24, G4H * H_);
  k_packW<<<2048, 256, 0, stream>>>(whh1, Whh1f, H_, 24, G4H * H_);
  k_packX<<<4096, 256, 0, stream>>>(x, Xf);
  k_bias<<<12, 256, 0, stream>>>(bih0, bhh0, bsum0);
  k_bias<<<12, 256, 0, stream>>>(bih1, bhh1, bsum1);
  k_zero<<<1280, 256, 0, stream>>>((int4*)fl, (int)(zeroBytes / 16));

  k_lstm<<<192, 512, SMEM_BYTES, stream>>>(Xf, Wih0f, Whh0f, Wih1f, Whh1f,
                                           bsum0, bsum1, ring0c, ring1c,
                                           wf0, wf1, gf0, gf1, out);
}